// Round 12
// baseline (315.615 us; speedup 1.0000x reference)
//
#include <hip/hip_runtime.h>
#include <hip/hip_bf16.h>

// Problem constants:
//   N_NODES=100000, MAX_DEG=128, NODE_DIM=256, BATCH=4096, NUM_SAMPLES=32
//   group_dim=4, dummy id = 99999
// Output d_out: FLOAT32, concat sel[4096*32], att[4096*32], numnz[4096], dummy[4096];
//               ref values are bf16-rounded -> write bf16-RNE-rounded f32.
//
// R12 == R10 resubmitted again (two GPU-acquisition timeouts; never ran).
// Group-16 hybrid. r7 (121us): coalesced row reads but 64-lane f64
// butterfly per neighbor (LDS-pipe bound, 131072 conflicts). r9 (134us):
// no shuffles but lane-divergent gather = 64 cache-line lookups per load
// instr (TA-bound, VALU 20%). Now: 16-lane group owns one neighbor row
// (256B-contiguous chunks, r7 coalescing), 4-step in-group butterfly,
// 2-step cross-group lexicographic argmin (= the group-of-4 argmin).
// l stored chunk-transposed in LDS so phase-2 reads are conflict-free b64.

constexpr int D        = 256;
constexpr int V        = 4096;
constexpr int MAXDEG   = 128;
constexpr int S        = 32;
constexpr int DUMMY_ID = 99999;

constexpr int OFF_SEL  = 0;
constexpr int OFF_ATT  = V * S;          // 131072
constexpr int OFF_NNZ  = 2 * V * S;      // 262144
constexpr int OFF_DMY  = 2 * V * S + V;  // 266240

__device__ __forceinline__ float bf16_round_f32(float f) {
    unsigned int u = __float_as_uint(f);
    u += 0x7FFFu + ((u >> 16) & 1u);   // RNE to bf16
    u &= 0xFFFF0000u;
    return __uint_as_float(u);
}

__global__ __launch_bounds__(256, 8) void fused_k(
    const int* __restrict__ adj, const float* __restrict__ features,
    const int* __restrict__ ids, const float* __restrict__ W,
    const float* __restrict__ bias, float* __restrict__ out)
{
    const int tid  = threadIdx.x;
    const int lane = tid & 63;
    const int wave = tid >> 6;
    const int v    = blockIdx.x;

    __shared__ float  vf[D];     // features[ids[v]]
    __shared__ double lshT[D];   // l row, chunk-transposed (see below)
    __shared__ int    cnt;
    if (tid == 0) cnt = 0;

    const int node = ids[v];
    vf[tid] = features[(size_t)node * D + tid];
    if (tid < S) out[OFF_ATT + v * S + tid] = 1.0f;   // att is constant 1.0
    __syncthreads();

    // Phase 1 (identical accumulation order to r7/r9, proven absmax 0):
    // l[tid] = b[tid] + sum_d vf[d]*W[d][tid], 4 partial f64 accumulators.
    {
        double a0 = (double)bias[tid], a1 = 0.0, a2 = 0.0, a3 = 0.0;
        #pragma unroll 2
        for (int d = 0; d < D; d += 4) {
            a0 = fma((double)vf[d    ], (double)W[(d    ) * D + tid], a0);
            a1 = fma((double)vf[d + 1], (double)W[(d + 1) * D + tid], a1);
            a2 = fma((double)vf[d + 2], (double)W[(d + 2) * D + tid], a2);
            a3 = fma((double)vf[d + 3], (double)W[(d + 3) * D + tid], a3);
        }
        const double lval = (a0 + a1) + (a2 + a3);
        // dim tid = c*64 + l16*4 + k  ->  slot c*64 + k*16 + l16
        // (phase-2 lane l16 then reads stride-8B across lanes: conflict-free)
        const int c = tid >> 6, rem = tid & 63;
        lshT[(c << 6) + ((rem & 3) << 4) + (rem >> 2)] = lval;
    }
    __syncthreads();

    // Phase 2: wave handles samples [8w, 8w+8). 16-lane group g owns neighbor
    // 4s+g; lane l16 covers dims {c*64 + l16*4 + k}. Row read = 4 chunks of
    // 256B contiguous per group (r7-grade coalescing).
    const int l16 = lane & 15;
    const int g   = lane >> 4;
    const int* arow = adj + (size_t)node * MAXDEG;

    int localcnt = 0;   // meaningful on lane 0 only

    #pragma unroll 2
    for (int s8 = 0; s8 < 8; ++s8) {
        const int s  = wave * 8 + s8;
        const int nb = arow[4 * s + g];            // uniform within group
        const float* r = features + (size_t)nb * D + (l16 << 2);

        const float4 x0 = *reinterpret_cast<const float4*>(r);
        const float4 x1 = *reinterpret_cast<const float4*>(r + 64);
        const float4 x2 = *reinterpret_cast<const float4*>(r + 128);
        const float4 x3 = *reinterpret_cast<const float4*>(r + 192);

        double pa = 0.0, pb = 0.0, pc = 0.0, pd = 0.0;
        // chunk 0
        pa = fma(lshT[      l16      ], (double)x0.x, pa);
        pb = fma(lshT[      l16 + 16 ], (double)x0.y, pb);
        pc = fma(lshT[      l16 + 32 ], (double)x0.z, pc);
        pd = fma(lshT[      l16 + 48 ], (double)x0.w, pd);
        // chunk 1
        pa = fma(lshT[ 64 + l16      ], (double)x1.x, pa);
        pb = fma(lshT[ 64 + l16 + 16 ], (double)x1.y, pb);
        pc = fma(lshT[ 64 + l16 + 32 ], (double)x1.z, pc);
        pd = fma(lshT[ 64 + l16 + 48 ], (double)x1.w, pd);
        // chunk 2
        pa = fma(lshT[128 + l16      ], (double)x2.x, pa);
        pb = fma(lshT[128 + l16 + 16 ], (double)x2.y, pb);
        pc = fma(lshT[128 + l16 + 32 ], (double)x2.z, pc);
        pd = fma(lshT[128 + l16 + 48 ], (double)x2.w, pd);
        // chunk 3
        pa = fma(lshT[192 + l16      ], (double)x3.x, pa);
        pb = fma(lshT[192 + l16 + 16 ], (double)x3.y, pb);
        pc = fma(lshT[192 + l16 + 32 ], (double)x3.z, pc);
        pd = fma(lshT[192 + l16 + 48 ], (double)x3.w, pd);

        double t = (pa + pb) + (pc + pd);
        // in-group 16-lane butterfly sum (4 steps)
        #pragma unroll
        for (int off = 1; off < 16; off <<= 1) t += __shfl_xor(t, off);
        double bs = fmax(t, 0.0);                  // relu

        // cross-group lexicographic (score, pos) min = grouped argmin with
        // first-index tie-break (pos = position within the group of 4)
        int bp = g, bid = nb;
        #pragma unroll
        for (int off = 16; off < 64; off <<= 1) {
            const double so = __shfl_xor(bs,  off);
            const int    po = __shfl_xor(bp,  off);
            const int    io = __shfl_xor(bid, off);
            if (so < bs || (so == bs && po < bp)) { bs = so; bp = po; bid = io; }
        }

        if (lane == 0) {
            out[OFF_SEL + v * S + s] = bf16_round_f32((float)bid);
            if (bid != DUMMY_ID) ++localcnt;
        }
    }

    if (lane == 0 && localcnt) atomicAdd(&cnt, localcnt);
    __syncthreads();
    if (tid == 0) {
        const float c = (float)cnt;   // 0..32, exact
        out[OFF_NNZ + v] = c;
        out[OFF_DMY + v] = c;
    }
}

extern "C" void kernel_launch(void* const* d_in, const int* in_sizes, int n_in,
                              void* d_out, int out_size, void* d_ws, size_t ws_size,
                              hipStream_t stream)
{
    const int*   adj      = (const int*)d_in[0];
    const float* features = (const float*)d_in[1];
    const int*   ids      = (const int*)d_in[2];
    const float* W        = (const float*)d_in[3];
    const float* bias     = (const float*)d_in[4];
    (void)d_ws; (void)ws_size;  // unused

    float* out = (float*)d_out;

    fused_k<<<V, 256, 0, stream>>>(adj, features, ids, W, bias, out);
}

// Round 13
// 256.396 us; speedup vs baseline: 1.2310x; 1.2310x over previous
//
#include <hip/hip_runtime.h>
#include <hip/hip_bf16.h>

// Problem constants:
//   N_NODES=100000, MAX_DEG=128, NODE_DIM=256, BATCH=4096, NUM_SAMPLES=32
//   group_dim=4, dummy id = 99999
// Output d_out: FLOAT32, concat sel[4096*32], att[4096*32], numnz[4096], dummy[4096];
//               ref values are bf16-rounded -> write bf16-RNE-rounded f32.
//
// R13: r7 structure (traffic-optimal whole-row wave-cooperative reads,
// 265MB fill traffic) with 8 concurrent neighbor chains (2 argmin groups
// per iteration) and launch_bounds(256,4) so the allocator can pipeline.
// r7's VGPR=32 proved it had zero pipelining headroom (4 rows in flight,
// 2.19 TB/s); r12 showed the fill-BW ceiling is >=2.74 TB/s. All rounds:
// dur == hbm_bytes/BW exactly -> raise MLP at constant traffic.

constexpr int D        = 256;
constexpr int V        = 4096;
constexpr int MAXDEG   = 128;
constexpr int S        = 32;
constexpr int DUMMY_ID = 99999;

constexpr int OFF_SEL  = 0;
constexpr int OFF_ATT  = V * S;          // 131072
constexpr int OFF_NNZ  = 2 * V * S;      // 262144
constexpr int OFF_DMY  = 2 * V * S + V;  // 266240

__device__ __forceinline__ float bf16_round_f32(float f) {
    unsigned int u = __float_as_uint(f);
    u += 0x7FFFu + ((u >> 16) & 1u);   // RNE to bf16
    u &= 0xFFFF0000u;
    return __uint_as_float(u);
}

// One block per v. Phase 1: l[v] = features[ids[v]] @ W + b (f64, into LDS).
// Phase 2: wave w scores neighbors [32w,32w+32): 4 iterations x 8 chains
// (= 2 groups of 4). Per-neighbor math bit-identical to r7 (passed, absmax 0).
__global__ __launch_bounds__(256, 4) void fused_k(
    const int* __restrict__ adj, const float* __restrict__ features,
    const int* __restrict__ ids, const float* __restrict__ W,
    const float* __restrict__ bias, float* __restrict__ out)
{
    const int v    = blockIdx.x;
    const int tid  = threadIdx.x;
    const int lane = tid & 63;
    const int wave = tid >> 6;

    __shared__ float  vf[D];     // features[ids[v]]
    __shared__ double lsh[D];    // l row (f64)
    __shared__ int cnt;
    if (tid == 0) cnt = 0;

    const int node = ids[v];
    vf[tid] = features[(size_t)node * D + tid];
    if (tid < S) out[OFF_ATT + v * S + tid] = 1.0f;   // att is constant 1.0
    __syncthreads();

    // Phase 1: l[j] = b[j] + sum_d vf[d]*W[d][j], 4 partial f64 accumulators
    {
        double a0 = (double)bias[tid], a1 = 0.0, a2 = 0.0, a3 = 0.0;
        #pragma unroll 4
        for (int d = 0; d < D; d += 4) {
            a0 = fma((double)vf[d    ], (double)W[(d    ) * D + tid], a0);
            a1 = fma((double)vf[d + 1], (double)W[(d + 1) * D + tid], a1);
            a2 = fma((double)vf[d + 2], (double)W[(d + 2) * D + tid], a2);
            a3 = fma((double)vf[d + 3], (double)W[(d + 3) * D + tid], a3);
        }
        lsh[tid] = (a0 + a1) + (a2 + a3);
    }
    __syncthreads();

    // Phase 2
    const double2 l01 = *reinterpret_cast<const double2*>(&lsh[lane * 4]);
    const double2 l23 = *reinterpret_cast<const double2*>(&lsh[lane * 4 + 2]);
    const int* arow = adj + (size_t)node * MAXDEG + wave * 32;

    int localcnt = 0;

    #pragma unroll 1
    for (int gi = 0; gi < 4; ++gi) {
        // 2 groups = 8 neighbor ids (uniform loads)
        const int4 nA = *reinterpret_cast<const int4*>(arow + 8 * gi);
        const int4 nB = *reinterpret_cast<const int4*>(arow + 8 * gi + 4);

        // 8 independent whole-row gathers, wave-cooperative (1KB contiguous each)
        const float4 f0 = *reinterpret_cast<const float4*>(features + (size_t)nA.x * D + lane * 4);
        const float4 f1 = *reinterpret_cast<const float4*>(features + (size_t)nA.y * D + lane * 4);
        const float4 f2 = *reinterpret_cast<const float4*>(features + (size_t)nA.z * D + lane * 4);
        const float4 f3 = *reinterpret_cast<const float4*>(features + (size_t)nA.w * D + lane * 4);
        const float4 f4 = *reinterpret_cast<const float4*>(features + (size_t)nB.x * D + lane * 4);
        const float4 f5 = *reinterpret_cast<const float4*>(features + (size_t)nB.y * D + lane * 4);
        const float4 f6 = *reinterpret_cast<const float4*>(features + (size_t)nB.z * D + lane * 4);
        const float4 f7 = *reinterpret_cast<const float4*>(features + (size_t)nB.w * D + lane * 4);

        // per-neighbor f64 dot partial — same fma nest as r7 (bit-identical)
        double p0 = fma(l01.x, (double)f0.x, fma(l01.y, (double)f0.y,
                    fma(l23.x, (double)f0.z, l23.y * (double)f0.w)));
        double p1 = fma(l01.x, (double)f1.x, fma(l01.y, (double)f1.y,
                    fma(l23.x, (double)f1.z, l23.y * (double)f1.w)));
        double p2 = fma(l01.x, (double)f2.x, fma(l01.y, (double)f2.y,
                    fma(l23.x, (double)f2.z, l23.y * (double)f2.w)));
        double p3 = fma(l01.x, (double)f3.x, fma(l01.y, (double)f3.y,
                    fma(l23.x, (double)f3.z, l23.y * (double)f3.w)));
        double p4 = fma(l01.x, (double)f4.x, fma(l01.y, (double)f4.y,
                    fma(l23.x, (double)f4.z, l23.y * (double)f4.w)));
        double p5 = fma(l01.x, (double)f5.x, fma(l01.y, (double)f5.y,
                    fma(l23.x, (double)f5.z, l23.y * (double)f5.w)));
        double p6 = fma(l01.x, (double)f6.x, fma(l01.y, (double)f6.y,
                    fma(l23.x, (double)f6.z, l23.y * (double)f6.w)));
        double p7 = fma(l01.x, (double)f7.x, fma(l01.y, (double)f7.y,
                    fma(l23.x, (double)f7.z, l23.y * (double)f7.w)));

        // 64-lane butterfly, 8 independent chains interleaved (same per-chain order)
        #pragma unroll
        for (int off = 32; off; off >>= 1) {
            p0 += __shfl_xor(p0, off);
            p1 += __shfl_xor(p1, off);
            p2 += __shfl_xor(p2, off);
            p3 += __shfl_xor(p3, off);
            p4 += __shfl_xor(p4, off);
            p5 += __shfl_xor(p5, off);
            p6 += __shfl_xor(p6, off);
            p7 += __shfl_xor(p7, off);
        }

        const double s0 = fmax(p0, 0.0), s1 = fmax(p1, 0.0);
        const double s2 = fmax(p2, 0.0), s3 = fmax(p3, 0.0);
        const double s4 = fmax(p4, 0.0), s5 = fmax(p5, 0.0);
        const double s6 = fmax(p6, 0.0), s7 = fmax(p7, 0.0);

        // grouped argmin, strict < = first-index tie-break (select chains)
        double bsA = s0; int selA = nA.x;
        if (s1 < bsA) { bsA = s1; selA = nA.y; }
        if (s2 < bsA) { bsA = s2; selA = nA.z; }
        if (s3 < bsA) { bsA = s3; selA = nA.w; }

        double bsB = s4; int selB = nB.x;
        if (s5 < bsB) { bsB = s5; selB = nB.y; }
        if (s6 < bsB) { bsB = s6; selB = nB.z; }
        if (s7 < bsB) { bsB = s7; selB = nB.w; }

        if (lane == 0) {
            const int sbase = wave * 8 + 2 * gi;
            out[OFF_SEL + v * S + sbase    ] = bf16_round_f32((float)selA);
            out[OFF_SEL + v * S + sbase + 1] = bf16_round_f32((float)selB);
            localcnt += (selA != DUMMY_ID) + (selB != DUMMY_ID);
        }
    }

    if (lane == 0 && localcnt) atomicAdd(&cnt, localcnt);
    __syncthreads();
    if (tid == 0) {
        const float c = (float)cnt;   // 0..32, exact
        out[OFF_NNZ + v] = c;
        out[OFF_DMY + v] = c;
    }
}

extern "C" void kernel_launch(void* const* d_in, const int* in_sizes, int n_in,
                              void* d_out, int out_size, void* d_ws, size_t ws_size,
                              hipStream_t stream)
{
    const int*   adj      = (const int*)d_in[0];
    const float* features = (const float*)d_in[1];
    const int*   ids      = (const int*)d_in[2];
    const float* W        = (const float*)d_in[3];
    const float* bias     = (const float*)d_in[4];
    (void)d_ws; (void)ws_size;  // unused

    float* out = (float*)d_out;

    fused_k<<<V, 256, 0, stream>>>(adj, features, ids, W, bias, out);
}